// Round 11
// baseline (341.076 us; speedup 1.0000x reference)
//
#include <hip/hip_runtime.h>
#include <hip/hip_bf16.h>
#include <math.h>

// y[M,N] = x[M,K] . W[N,K]^T,  W = q*s + z
// Pass 1 (fused): convert x->bf16 + dequant W->bf16 into d_ws.
// Pass 2: 256x256-tile bf16 GEMM, 16 waves (4x4, 64x64 per wave) for
//         4 waves/SIMD TLP, counted vmcnt(3), 2 barriers/K-tile, setprio,
//         3-bit LDS XOR-swizzle, 2D XCD raster. 1024 thr, 128 KiB LDS.
// Fallbacks: m97-structure 128x128 GEMM; fully-fused round-1 kernel.

typedef __bf16 bf16x8 __attribute__((ext_vector_type(8)));
typedef float f32x4 __attribute__((ext_vector_type(4)));

#define GL(gsrc, ldst)                                                       \
    __builtin_amdgcn_global_load_lds(                                        \
        (__attribute__((address_space(1))) void*)(gsrc),                     \
        (__attribute__((address_space(3))) void*)(ldst), 16, 0, 0)

// ---------------- pass 1: fused x-convert + W-dequant ----------------
__global__ void prep_ab(const float* __restrict__ X, const int* __restrict__ Q,
                        const float* __restrict__ S, const float* __restrict__ Z,
                        __bf16* __restrict__ Xo, __bf16* __restrict__ Wo,
                        long n8x, int N, int K, int G)
{
    const int K8 = K >> 3;
    const long n8w = (long)N * K8;
    const long tot = n8x + n8w;
    long i = (long)blockIdx.x * blockDim.x + threadIdx.x;
    const long stride = (long)gridDim.x * blockDim.x;
    for (; i < tot; i += stride) {
        if (i < n8x) {
            const float4 v0 = ((const float4*)X)[i * 2];
            const float4 v1 = ((const float4*)X)[i * 2 + 1];
            bf16x8 u;
            u[0] = (__bf16)v0.x; u[1] = (__bf16)v0.y;
            u[2] = (__bf16)v0.z; u[3] = (__bf16)v0.w;
            u[4] = (__bf16)v1.x; u[5] = (__bf16)v1.y;
            u[6] = (__bf16)v1.z; u[7] = (__bf16)v1.w;
            ((bf16x8*)Xo)[i] = u;
        } else {
            const long j = i - n8x;
            const int n  = (int)(j / K8);
            const int kc = (int)(j - (long)n * K8);
            const int g  = (kc << 3) / G;
            const float s = S[(size_t)g * N + n];
            const float z = Z[(size_t)g * N + n];
            const int4 q0 = ((const int4*)Q)[j * 2];
            const int4 q1 = ((const int4*)Q)[j * 2 + 1];
            bf16x8 u;
            u[0] = (__bf16)((float)q0.x * s + z);
            u[1] = (__bf16)((float)q0.y * s + z);
            u[2] = (__bf16)((float)q0.z * s + z);
            u[3] = (__bf16)((float)q0.w * s + z);
            u[4] = (__bf16)((float)q1.x * s + z);
            u[5] = (__bf16)((float)q1.y * s + z);
            u[6] = (__bf16)((float)q1.z * s + z);
            u[7] = (__bf16)((float)q1.w * s + z);
            ((bf16x8*)Wo)[j] = u;
        }
    }
}

// ---------------- pass 2: 256x256 16-wave GEMM ----------------
// LDS map (bytes): A: (buf*2+half)*16384, 0..65535 ; B: 65536 + same.
// Swizzle (3-bit): phys(r, c16) = r*128 + ((c16 ^ (r&7)) << 4); write side =
// same involution on the global SOURCE column per lane. Conflicts: 0 (R4).
// 16 waves as 4(m)x4(n); wave tile 64x64; per wave per K-tile: 16 ds_read,
// 32 MFMA, 4 GL (1/chunk: cb = w*1024 covers the 16 chunks of a half-tile).
// Barrier ledger (2/K-tile): pre-stage BAR (each wave passed its own
// lgkm(0) -> all tile-T reads drained before T+2 stages overwrite buf);
// post-VMC BAR (T+1 staged & visible before next tile's reads).
// VMC(3): outstanding/wave at wait = 3(T+1 stages, issued T-1 ph4)
// + 1(B-h1 T+1, issued T ph1) + 3(T+2 stages, just issued) = 7 -> 3
// drains all T+1-targeted loads, keeps T+2's 3 in flight.

#define SB0 __builtin_amdgcn_sched_barrier(0)
#define PH_BAR do { SB0; __builtin_amdgcn_s_barrier(); SB0; } while (0)
#define LGKM(n) do { asm volatile("s_waitcnt lgkmcnt(" #n ")" ::: "memory");  \
                     SB0; } while (0)
#define VMC(n)  do { asm volatile("s_waitcnt vmcnt(" #n ")" ::: "memory");    \
                     SB0; } while (0)

#define STAGE_A(BUF, H, T)                                                    \
    GL(pa + (H) * hstep + (size_t)(T) * 64, sm + ((BUF)*2+(H))*16384 + cb)
#define STAGE_B(BUF, H, T)                                                    \
    GL(pb + (H) * hstep + (size_t)(T) * 64, sm + 65536 + ((BUF)*2+(H))*16384 + cb)

#define RDA(KS, BUF)                                                          \
    _Pragma("unroll")                                                         \
    for (int mq = 0; mq < 4; ++mq) {                                          \
        const int r_ = (wm4 & 1) * 64 + mq * 16 + lr;                         \
        const int rb_ = ((BUF)*2 + ha) * 16384 + r_ * 128;                    \
        const int sw_ = (r_ & 7) << 4;                                        \
        af[mq] = *(const bf16x8*)(sm + rb_ + ((((KS)*4 + lk) * 16) ^ sw_));   \
    }
#define RDB(KS, BUF)                                                          \
    _Pragma("unroll")                                                         \
    for (int nq = 0; nq < 4; ++nq) {                                          \
        const int r_ = (wn4 & 1) * 64 + nq * 16 + lr;                         \
        const int rb_ = 65536 + ((BUF)*2 + hb) * 16384 + r_ * 128;            \
        const int sw_ = (r_ & 7) << 4;                                        \
        bq[nq] = *(const bf16x8*)(sm + rb_ + ((((KS)*4 + lk) * 16) ^ sw_));   \
    }
#define QUAD16 do {                                                           \
    __builtin_amdgcn_s_setprio(1);                                            \
    _Pragma("unroll")                                                         \
    for (int mq = 0; mq < 4; ++mq)                                            \
        _Pragma("unroll")                                                     \
        for (int nq = 0; nq < 4; ++nq)                                        \
            acc[mq][nq] = __builtin_amdgcn_mfma_f32_16x16x32_bf16(            \
                af[mq], bq[nq], acc[mq][nq], 0, 0, 0);                        \
    __builtin_amdgcn_s_setprio(0); } while (0)

// MODE 0: full staging + vmcnt(3); MODE 1: B-h1 stage only + vmcnt(0); MODE 2: bare.
#define TILE(T, BUF, MODE) do {                                               \
    RDA(0, BUF);                                                              \
    RDB(0, BUF);                                                              \
    if ((MODE) < 2) { STAGE_B((BUF)^1, 1, (T)+1); }                           \
    SB0;                                                                      \
    LGKM(0);                                                                  \
    QUAD16;                                                                   \
    RDA(1, BUF);              /* WAR on af/bq: QUAD16 already issued */       \
    RDB(1, BUF);                                                              \
    SB0;                                                                      \
    LGKM(0);                                                                  \
    QUAD16;                                                                   \
    PH_BAR;   /* every wave passed lgkm(0): block-wide read drain */          \
    if ((MODE) == 0) { STAGE_B(BUF, 0, (T)+2);                                \
                       STAGE_A(BUF, 0, (T)+2); STAGE_A(BUF, 1, (T)+2);        \
                       VMC(3); }                                              \
    else if ((MODE) == 1) { VMC(0); }                                         \
    PH_BAR;   /* T+1 staged & visible */                                      \
} while (0)

__global__ __launch_bounds__(1024, 4)
void gemm16w(const __bf16* __restrict__ A, const __bf16* __restrict__ B,
             float* __restrict__ Y, int M, int N, int K)
{
    extern __shared__ __align__(16) char sm[];
    const int tid  = threadIdx.x;
    const int lane = tid & 63;
    const int w    = tid >> 6;      // wave 0..15
    const int wm4  = w >> 2;        // 0..3
    const int wn4  = w & 3;         // 0..3
    const int ha   = wm4 >> 1;      // A half
    const int hb   = wn4 >> 1;      // B half
    const int lr   = lane & 15;
    const int lk   = lane >> 4;
    const int nbn  = N / 256;
    const int nbm  = M / 256;
    const int nt   = K / 64;

    // 2D XCD rasterization: 8 XCDs (bid&7) as 4(m)x2(n) rectangles.
    int bm, bn;
    if ((nbm & 3) == 0 && (nbn & 1) == 0) {
        const int xcd = blockIdx.x & 7;
        const int p   = blockIdx.x >> 3;
        const int rm  = nbm >> 2;
        const int rn  = nbn >> 1;
        bm = (xcd >> 1) * rm + p / rn;
        bn = (xcd & 1) * rn + p % rn;
    } else {
        bm = blockIdx.x / nbn;
        bn = blockIdx.x - bm * nbn;
    }

    // staging source: lane l sources col16 = (l&7)^(l>>3) (3-bit involution)
    const int ls   = (lane & 56) | ((lane ^ (lane >> 3)) & 7);
    const int row0 = w * 8 + (ls >> 3);           // row within 128-row half
    const int colg = (ls & 7) * 8;
    const __bf16* pa = A + (size_t)(bm * 256 + row0) * K + colg;
    const __bf16* pb = B + (size_t)(bn * 256 + row0) * K + colg;
    const size_t hstep = (size_t)128 * K;
    const int cb = w * 1024;                      // 1 KiB chunk per wave

    f32x4  acc[4][4] = {};
    bf16x8 af[4];
    bf16x8 bq[4];

    // prologue: tile0 (4 half-tiles) + b0,a0,a1 of tile1 (3 half-tiles)
    STAGE_A(0, 0, 0); STAGE_A(0, 1, 0); STAGE_B(0, 0, 0); STAGE_B(0, 1, 0);
    STAGE_B(1, 0, 1); STAGE_A(1, 0, 1); STAGE_A(1, 1, 1);
    VMC(3);
    PH_BAR;

    for (int t = 0; t + 3 < nt; t += 2) {
        TILE(t,     0, 0);
        TILE(t + 1, 1, 0);
    }
    TILE(nt - 2, 0, 1);
    TILE(nt - 1, 1, 2);

    // epilogue: C/D layout col=lane&15, row=(lane>>4)*4+reg
    const int rowb = bm * 256 + wm4 * 64;
    const int colb = bn * 256 + wn4 * 64;
#pragma unroll
    for (int m = 0; m < 4; ++m) {
#pragma unroll
        for (int n = 0; n < 4; ++n) {
            float* yp = Y + (size_t)(rowb + m * 16 + lk * 4) * N + colb + n * 16 + lr;
#pragma unroll
            for (int r = 0; r < 4; ++r)
                yp[(size_t)r * N] = acc[m][n][r];
        }
    }
}

// ---------------- fallback: m97-structure 128x128 GEMM ----------------
#define TM 128
#define TN 128
#define TK 64

__global__ __launch_bounds__(256)
void gemm_bf16_bt(const __bf16* __restrict__ A, const __bf16* __restrict__ B,
                  float* __restrict__ Y, int M, int N, int K)
{
    __shared__ __attribute__((aligned(16))) __bf16 Al[TM * TK];
    __shared__ __attribute__((aligned(16))) __bf16 Bl[TN * TK];

    const int tid  = threadIdx.x;
    const int lane = tid & 63;
    const int wv   = tid >> 6;
    const int nbn  = N / TN;
    const int bm   = blockIdx.x / nbn;
    const int bn   = blockIdx.x - bm * nbn;

    const __bf16* ga = A + ((size_t)(bm * TM + wv * 32 + (lane >> 3))) * K + (lane & 7) * 8;
    const __bf16* gb = B + ((size_t)(bn * TN + wv * 32 + (lane >> 3))) * K + (lane & 7) * 8;

    const int lr = lane & 15;
    const int lk = lane >> 4;
    const int wmm = (wv >> 1) * 64;
    const int wnn = (wv & 1) * 64;

    f32x4 acc[4][4] = {};
    const int ntile = K / TK;
    for (int t = 0; t < ntile; ++t) {
#pragma unroll
        for (int i = 0; i < 4; ++i)
            GL(ga + (size_t)i * 8 * K, &Al[(wv * 32 + i * 8) * TK]);
#pragma unroll
        for (int i = 0; i < 4; ++i)
            GL(gb + (size_t)i * 8 * K, &Bl[(wv * 32 + i * 8) * TK]);
        __syncthreads();
#pragma unroll
        for (int ks = 0; ks < 2; ++ks) {
            bf16x8 a2[4], b2[4];
#pragma unroll
            for (int i = 0; i < 4; ++i)
                a2[i] = *(const bf16x8*)&Al[(wmm + i * 16 + lr) * TK + ks * 32 + lk * 8];
#pragma unroll
            for (int j = 0; j < 4; ++j)
                b2[j] = *(const bf16x8*)&Bl[(wnn + j * 16 + lr) * TK + ks * 32 + lk * 8];
#pragma unroll
            for (int i = 0; i < 4; ++i)
#pragma unroll
                for (int j = 0; j < 4; ++j)
                    acc[i][j] = __builtin_amdgcn_mfma_f32_16x16x32_bf16(
                        a2[i], b2[j], acc[i][j], 0, 0, 0);
        }
        __syncthreads();
        ga += TK; gb += TK;
    }
    const int rowb = lk * 4;
#pragma unroll
    for (int i = 0; i < 4; ++i)
#pragma unroll
        for (int j = 0; j < 4; ++j) {
            const int col = bn * TN + wnn + j * 16 + lr;
            float* yp = Y + (size_t)(bm * TM + wmm + i * 16 + rowb) * N + col;
#pragma unroll
            for (int r = 0; r < 4; ++r)
                yp[(size_t)r * N] = acc[i][j][r];
        }
}

// ---------------- fallback: round-1 fused kernel (tiny ws) ----------------
__global__ __launch_bounds__(256, 2)
void qlin_fused(const float* __restrict__ X, const int* __restrict__ Q,
                const float* __restrict__ S, const float* __restrict__ Z,
                float* __restrict__ Y, int M, int N, int K, int G)
{
    __shared__ __attribute__((aligned(16))) __bf16 Al[TM * TK];
    __shared__ __attribute__((aligned(16))) __bf16 Bl[TN * TK];

    const int tid = threadIdx.x;
    const int nbn = N / TN;
    const int bm = blockIdx.x / nbn;
    const int bn = blockIdx.x % nbn;

    const float* ap[4];
    const int*   qp[4];
    int nIdx[4], ldsOff[4];
#pragma unroll
    for (int i = 0; i < 4; ++i) {
        const int c   = tid + i * 256;
        const int row = c >> 3;
        const int c8  = c & 7;
        ldsOff[i] = row * TK + (c8 ^ (row & 7)) * 8;
        ap[i]   = X + (size_t)(bm * TM + row) * K + c8 * 8;
        qp[i]   = Q + (size_t)(bn * TN + row) * K + c8 * 8;
        nIdx[i] = bn * TN + row;
    }
    const int lane = tid & 63;
    const int wv   = tid >> 6;
    const int wmm  = (wv >> 1) * 64;
    const int wnn  = (wv & 1) * 64;
    const int lr   = lane & 15;
    const int lk   = lane >> 4;

    f32x4 acc[4][4] = {};
    const int ntile = K / TK;
    const int gstep = G / TK;
    int g = 0, gc = 0;
    for (int t = 0; t < ntile; ++t) {
#pragma unroll
        for (int i = 0; i < 4; ++i) {
            const float4 v0 = *(const float4*)(ap[i]);
            const float4 v1 = *(const float4*)(ap[i] + 4);
            bf16x8 u;
            u[0] = (__bf16)v0.x; u[1] = (__bf16)v0.y;
            u[2] = (__bf16)v0.z; u[3] = (__bf16)v0.w;
            u[4] = (__bf16)v1.x; u[5] = (__bf16)v1.y;
            u[6] = (__bf16)v1.z; u[7] = (__bf16)v1.w;
            *(bf16x8*)&Al[ldsOff[i]] = u;
            ap[i] += TK;
        }
#pragma unroll
        for (int i = 0; i < 4; ++i) {
            const int4 q0 = *(const int4*)(qp[i]);
            const int4 q1 = *(const int4*)(qp[i] + 4);
            const float s = S[(size_t)g * N + nIdx[i]];
            const float z = Z[(size_t)g * N + nIdx[i]];
            bf16x8 u;
            u[0] = (__bf16)((float)q0.x * s + z);
            u[1] = (__bf16)((float)q0.y * s + z);
            u[2] = (__bf16)((float)q0.z * s + z);
            u[3] = (__bf16)((float)q0.w * s + z);
            u[4] = (__bf16)((float)q1.x * s + z);
            u[5] = (__bf16)((float)q1.y * s + z);
            u[6] = (__bf16)((float)q1.z * s + z);
            u[7] = (__bf16)((float)q1.w * s + z);
            *(bf16x8*)&Bl[ldsOff[i]] = u;
            qp[i] += TK;
        }
        __syncthreads();
#pragma unroll
        for (int ks = 0; ks < 2; ++ks) {
            bf16x8 a2[4], b2[4];
#pragma unroll
            for (int i = 0; i < 4; ++i) {
                const int row = wmm + i * 16 + lr;
                a2[i] = *(const bf16x8*)&Al[row * TK + ((ks * 4 + lk) ^ (row & 7)) * 8];
            }
#pragma unroll
            for (int j = 0; j < 4; ++j) {
                const int row = wnn + j * 16 + lr;
                b2[j] = *(const bf16x8*)&Bl[row * TK + ((ks * 4 + lk) ^ (row & 7)) * 8];
            }
#pragma unroll
            for (int i = 0; i < 4; ++i)
#pragma unroll
                for (int j = 0; j < 4; ++j)
                    acc[i][j] = __builtin_amdgcn_mfma_f32_16x16x32_bf16(
                        a2[i], b2[j], acc[i][j], 0, 0, 0);
        }
        __syncthreads();
        if (++gc == gstep) { gc = 0; ++g; }
    }
    const int rowb = lk * 4;
#pragma unroll
    for (int i = 0; i < 4; ++i)
#pragma unroll
        for (int j = 0; j < 4; ++j) {
            const int col = bn * TN + wnn + j * 16 + lr;
            float* yp = Y + (size_t)(bm * TM + wmm + i * 16 + rowb) * N + col;
#pragma unroll
            for (int r = 0; r < 4; ++r)
                yp[(size_t)r * N] = acc[i][j][r];
        }
}

extern "C" void kernel_launch(void* const* d_in, const int* in_sizes, int n_in,
                              void* d_out, int out_size, void* d_ws, size_t ws_size,
                              hipStream_t stream)
{
    const float* X  = (const float*)d_in[0];
    const int*   Q  = (const int*)d_in[1];
    const float* S  = (const float*)d_in[2];
    const float* Z  = (const float*)d_in[3];
    float*       Y  = (float*)d_out;

    const long long MK = in_sizes[0];
    const long long NK = in_sizes[1];
    const long long GN = in_sizes[2];
    const int G = (int)(NK / GN);
    const long long kk = NK * MK / (long long)out_size;
    const int K = (int)llround(sqrt((double)kk));
    const int M = (int)(MK / K);
    const int N = (int)(NK / K);

    const size_t need = ((size_t)M * K + (size_t)N * K) * sizeof(__bf16);
    if (ws_size >= need) {
        __bf16* Xbf = (__bf16*)d_ws;
        __bf16* Wbf = Xbf + (size_t)M * K;
        prep_ab<<<2048, 256, 0, stream>>>(X, Q, S, Z, Xbf, Wbf,
                                          (long)M * K / 8, N, K, G);

        bool done = false;
        if ((M % 256 == 0) && (N % 256 == 0) && (K % 128 == 0) && (K >= 256)) {
            (void)hipFuncSetAttribute((const void*)gemm16w,
                                      hipFuncAttributeMaxDynamicSharedMemorySize,
                                      131072);
            (void)hipGetLastError();   // clear
            gemm16w<<<(M / 256) * (N / 256), 1024, 131072, stream>>>(Xbf, Wbf, Y, M, N, K);
            done = (hipGetLastError() == hipSuccess);
        }
        if (!done) {
            gemm_bf16_bt<<<(M / TM) * (N / TN), 256, 0, stream>>>(Xbf, Wbf, Y, M, N, K);
        }
    } else {
        qlin_fused<<<(M / TM) * (N / TN), 256, 0, stream>>>(X, Q, S, Z, Y, M, N, K, G);
    }
}

// Round 12
// 273.465 us; speedup vs baseline: 1.2472x; 1.2472x over previous
//
#include <hip/hip_runtime.h>
#include <hip/hip_bf16.h>
#include <math.h>

// y[M,N] = x[M,K] . W[N,K]^T,  W = q*s + z
// Pass 1 (fused): convert x->bf16 + dequant W->bf16 into d_ws.
// Pass 2: 256x256-tile bf16 GEMM (R8 structure), NO manual lgkmcnt and NO
//         sched_barrier fences -- compiler emits fine-grained counted waits;
//         raw s_barrier w/ memory clobber; counted vmcnt(6); setprio;
//         3-bit LDS XOR-swizzle; 2D XCD raster. 512 thr, 128 KiB LDS.
// Fallbacks: m97-structure 128x128 GEMM; fully-fused round-1 kernel.

typedef __bf16 bf16x8 __attribute__((ext_vector_type(8)));
typedef float f32x4 __attribute__((ext_vector_type(4)));

#define GL(gsrc, ldst)                                                       \
    __builtin_amdgcn_global_load_lds(                                        \
        (__attribute__((address_space(1))) void*)(gsrc),                     \
        (__attribute__((address_space(3))) void*)(ldst), 16, 0, 0)

// ---------------- pass 1: fused x-convert + W-dequant ----------------
__global__ void prep_ab(const float* __restrict__ X, const int* __restrict__ Q,
                        const float* __restrict__ S, const float* __restrict__ Z,
                        __bf16* __restrict__ Xo, __bf16* __restrict__ Wo,
                        long n8x, int N, int K, int G)
{
    const int K8 = K >> 3;
    const long n8w = (long)N * K8;
    const long tot = n8x + n8w;
    long i = (long)blockIdx.x * blockDim.x + threadIdx.x;
    const long stride = (long)gridDim.x * blockDim.x;
    for (; i < tot; i += stride) {
        if (i < n8x) {
            const float4 v0 = ((const float4*)X)[i * 2];
            const float4 v1 = ((const float4*)X)[i * 2 + 1];
            bf16x8 u;
            u[0] = (__bf16)v0.x; u[1] = (__bf16)v0.y;
            u[2] = (__bf16)v0.z; u[3] = (__bf16)v0.w;
            u[4] = (__bf16)v1.x; u[5] = (__bf16)v1.y;
            u[6] = (__bf16)v1.z; u[7] = (__bf16)v1.w;
            ((bf16x8*)Xo)[i] = u;
        } else {
            const long j = i - n8x;
            const int n  = (int)(j / K8);
            const int kc = (int)(j - (long)n * K8);
            const int g  = (kc << 3) / G;
            const float s = S[(size_t)g * N + n];
            const float z = Z[(size_t)g * N + n];
            const int4 q0 = ((const int4*)Q)[j * 2];
            const int4 q1 = ((const int4*)Q)[j * 2 + 1];
            bf16x8 u;
            u[0] = (__bf16)((float)q0.x * s + z);
            u[1] = (__bf16)((float)q0.y * s + z);
            u[2] = (__bf16)((float)q0.z * s + z);
            u[3] = (__bf16)((float)q0.w * s + z);
            u[4] = (__bf16)((float)q1.x * s + z);
            u[5] = (__bf16)((float)q1.y * s + z);
            u[6] = (__bf16)((float)q1.z * s + z);
            u[7] = (__bf16)((float)q1.w * s + z);
            ((bf16x8*)Wo)[j] = u;
        }
    }
}

// ---------------- pass 2: 256x256 compiler-scheduled GEMM ----------------
// LDS map (bytes): A: (buf*2+half)*16384, 0..65535 ; B: 65536 + same.
// Swizzle (3-bit): phys(r, c16) = r*128 + ((c16 ^ (r&7)) << 4); write side =
// same involution on the global SOURCE column per lane. Conflicts: 0 (R4).
// Scheduling: NO manual lgkmcnt, NO sched_barrier. The compiler inserts
// fine-grained counted lgkmcnt before each MFMA's operand use (m97-verified
// behavior); barriers are raw s_barrier with "memory" clobber so no memory
// op crosses them, but VALU/addressing/MFMA scheduling is free.
// Barrier ledger (3/K-tile, same as R8):
//   pre-QUAD(4,2) BAR: caps wave skew; any wave reaching it has (by its own
//     program order + in-order DS) completed waits for all tile-T reads
//     issued so far; stage writes for T+2 happen >= 1 barrier later.
//   pre-stage BAR: each wave's QUAD(4,2) operand waits dominate all its
//     earlier in-order DS reads -> all tile-T reads drained block-wide
//     before T+2 stages overwrite buf.
//   post-VMC BAR: T+1 staged & visible before next tile's reads.
// VMC(6): outstanding at wait = 14 -> 6 drains all T+1-targeted loads.

#define PH_BAR  asm volatile("s_barrier" ::: "memory")
#define VMC(n)  asm volatile("s_waitcnt vmcnt(" #n ")" ::: "memory")

#define STAGE_A(BUF, H, T) do {                                               \
    GL(pa0 + (H) * hstep + (size_t)(T) * 64, sm + (BUF)*32768 + (H)*16384 + cb0); \
    GL(pa1 + (H) * hstep + (size_t)(T) * 64, sm + (BUF)*32768 + (H)*16384 + cb1); } while (0)
#define STAGE_B(BUF, H, T) do {                                               \
    GL(pb0 + (H) * hstep + (size_t)(T) * 64, sm + 65536 + (BUF)*32768 + (H)*16384 + cb0); \
    GL(pb1 + (H) * hstep + (size_t)(T) * 64, sm + 65536 + (BUF)*32768 + (H)*16384 + cb1); } while (0)

#define RDA(RBASE, BUF)                                                       \
    _Pragma("unroll")                                                         \
    for (int mq = 0; mq < 4; ++mq) {                                          \
        const int r_ = (RBASE) + mq * 16 + lr;                                \
        const int rb_ = (BUF)*32768 + wm*16384 + r_*128;                      \
        const int sw_ = (r_ & 7) << 4;                                        \
        af[mq][0] = *(const bf16x8*)(sm + rb_ + ((lk*16) ^ sw_));             \
        af[mq][1] = *(const bf16x8*)(sm + rb_ + (((4+lk)*16) ^ sw_));         \
    }
#define RDB(N0, N1, BUF)                                                      \
    _Pragma("unroll")                                                         \
    for (int nq = (N0); nq < (N1); ++nq) {                                    \
        const int r_ = (wn & 1) * 64 + nq * 16 + lr;                          \
        const int rb_ = 65536 + (BUF)*32768 + (wn>>1)*16384 + r_*128;         \
        const int sw_ = (r_ & 7) << 4;                                        \
        bq[nq][0] = *(const bf16x8*)(sm + rb_ + ((lk*16) ^ sw_));             \
        bq[nq][1] = *(const bf16x8*)(sm + rb_ + (((4+lk)*16) ^ sw_));         \
    }
#define QUAD(MLO, NLO) do {                                                   \
    __builtin_amdgcn_s_setprio(1);                                            \
    _Pragma("unroll")                                                         \
    for (int mq = 0; mq < 4; ++mq)                                            \
        _Pragma("unroll")                                                     \
        for (int nq = 0; nq < 2; ++nq) {                                      \
            acc[(MLO)+mq][(NLO)+nq] = __builtin_amdgcn_mfma_f32_16x16x32_bf16(\
                af[mq][0], bq[(NLO)+nq][0], acc[(MLO)+mq][(NLO)+nq], 0,0,0);  \
            acc[(MLO)+mq][(NLO)+nq] = __builtin_amdgcn_mfma_f32_16x16x32_bf16(\
                af[mq][1], bq[(NLO)+nq][1], acc[(MLO)+mq][(NLO)+nq], 0,0,0);  \
        }                                                                     \
    __builtin_amdgcn_s_setprio(0); } while (0)

// MODE 0: full staging + vmcnt(6); MODE 1: B-h1 stage only + vmcnt(0); MODE 2: bare.
#define TILE(T, BUF, MODE) do {                                               \
    /* ph1: A-lo(8)+B-lo(4) reads; stage next-tile B-h1 */                    \
    RDA(0, BUF);                                                              \
    RDB(0, 2, BUF);                                                           \
    if ((MODE) < 2) { STAGE_B((BUF)^1, 1, (T)+1); }                           \
    QUAD(0, 0);                                                               \
    /* ph2: B-hi(4) reads (compiler interleaves with ph1 MFMA) */             \
    RDB(2, 4, BUF);                                                           \
    QUAD(0, 2);                                                               \
    /* ph3: A-hi(8) reads */                                                  \
    RDA(64, BUF);                                                             \
    PH_BAR;   /* caps wave skew */                                            \
    QUAD(4, 2);                                                               \
    PH_BAR;   /* pre-stage: all tile-T reads drained block-wide */            \
    if ((MODE) == 0) { STAGE_B(BUF, 0, (T)+2);                                \
                       STAGE_A(BUF, 0, (T)+2); STAGE_A(BUF, 1, (T)+2);        \
                       VMC(6); }                                              \
    else if ((MODE) == 1) { VMC(0); }                                         \
    PH_BAR;   /* post-VMC: t+1 staged & visible */                            \
    QUAD(4, 0);                                                               \
    /* no closing barrier: next-ph1 reads overlap ph4 MFMA */                 \
} while (0)

__global__ __launch_bounds__(512, 2)
void gemm8ph(const __bf16* __restrict__ A, const __bf16* __restrict__ B,
             float* __restrict__ Y, int M, int N, int K)
{
    extern __shared__ __align__(16) char sm[];
    const int tid  = threadIdx.x;
    const int lane = tid & 63;
    const int w    = tid >> 6;      // wave 0..7
    const int wm   = w >> 2;        // 0..1
    const int wn   = w & 3;         // 0..3
    const int lr   = lane & 15;
    const int lk   = lane >> 4;
    const int nbn  = N / 256;
    const int nbm  = M / 256;
    const int nt   = K / 64;

    // 2D XCD rasterization: 8 XCDs (bid&7) as 4(m)x2(n) rectangles.
    int bm, bn;
    if ((nbm & 3) == 0 && (nbn & 1) == 0) {
        const int xcd = blockIdx.x & 7;
        const int p   = blockIdx.x >> 3;
        const int rm  = nbm >> 2;
        const int rn  = nbn >> 1;
        bm = (xcd >> 1) * rm + p / rn;
        bn = (xcd & 1) * rn + p % rn;
    } else {
        bm = blockIdx.x / nbn;
        bn = blockIdx.x - bm * nbn;
    }

    // staging source: lane l sources col16 = (l&7)^(l>>3) (3-bit involution)
    const int ls    = (lane & 56) | ((lane ^ (lane >> 3)) & 7);
    const int rowA0 = w * 8 + (ls >> 3);
    const int rowA1 = 64 + w * 8 + (ls >> 3);
    const int colg  = (ls & 7) * 8;
    const __bf16* pa0 = A + (size_t)(bm * 256 + rowA0) * K + colg;
    const __bf16* pa1 = A + (size_t)(bm * 256 + rowA1) * K + colg;
    const __bf16* pb0 = B + (size_t)(bn * 256 + rowA0) * K + colg;
    const __bf16* pb1 = B + (size_t)(bn * 256 + rowA1) * K + colg;
    const size_t hstep = (size_t)128 * K;
    const int cb0 = w * 1024;
    const int cb1 = (8 + w) * 1024;

    f32x4  acc[8][4] = {};
    bf16x8 af[4][2];
    bf16x8 bq[4][2];

    // prologue: tile0 (4 half-tiles) + b0,a0,a1 of tile1 (3 half-tiles)
    STAGE_A(0, 0, 0); STAGE_A(0, 1, 0); STAGE_B(0, 0, 0); STAGE_B(0, 1, 0);
    STAGE_B(1, 0, 1); STAGE_A(1, 0, 1); STAGE_A(1, 1, 1);
    VMC(6);
    PH_BAR;

    for (int t = 0; t + 3 < nt; t += 2) {
        TILE(t,     0, 0);
        TILE(t + 1, 1, 0);
    }
    TILE(nt - 2, 0, 1);
    TILE(nt - 1, 1, 2);

    // epilogue: C/D layout col=lane&15, row=(lane>>4)*4+reg
    const int rowb = bm * 256 + wm * 128;
    const int colb = bn * 256 + wn * 64;
#pragma unroll
    for (int m = 0; m < 8; ++m) {
#pragma unroll
        for (int n = 0; n < 4; ++n) {
            float* yp = Y + (size_t)(rowb + m * 16 + lk * 4) * N + colb + n * 16 + lr;
#pragma unroll
            for (int r = 0; r < 4; ++r)
                yp[(size_t)r * N] = acc[m][n][r];
        }
    }
}

// ---------------- fallback: m97-structure 128x128 GEMM ----------------
#define TM 128
#define TN 128
#define TK 64

__global__ __launch_bounds__(256)
void gemm_bf16_bt(const __bf16* __restrict__ A, const __bf16* __restrict__ B,
                  float* __restrict__ Y, int M, int N, int K)
{
    __shared__ __attribute__((aligned(16))) __bf16 Al[TM * TK];
    __shared__ __attribute__((aligned(16))) __bf16 Bl[TN * TK];

    const int tid  = threadIdx.x;
    const int lane = tid & 63;
    const int wv   = tid >> 6;
    const int nbn  = N / TN;
    const int bm   = blockIdx.x / nbn;
    const int bn   = blockIdx.x - bm * nbn;

    const __bf16* ga = A + ((size_t)(bm * TM + wv * 32 + (lane >> 3))) * K + (lane & 7) * 8;
    const __bf16* gb = B + ((size_t)(bn * TN + wv * 32 + (lane >> 3))) * K + (lane & 7) * 8;

    const int lr = lane & 15;
    const int lk = lane >> 4;
    const int wmm = (wv >> 1) * 64;
    const int wnn = (wv & 1) * 64;

    f32x4 acc[4][4] = {};
    const int ntile = K / TK;
    for (int t = 0; t < ntile; ++t) {
#pragma unroll
        for (int i = 0; i < 4; ++i)
            GL(ga + (size_t)i * 8 * K, &Al[(wv * 32 + i * 8) * TK]);
#pragma unroll
        for (int i = 0; i < 4; ++i)
            GL(gb + (size_t)i * 8 * K, &Bl[(wv * 32 + i * 8) * TK]);
        __syncthreads();
#pragma unroll
        for (int ks = 0; ks < 2; ++ks) {
            bf16x8 a2[4], b2[4];
#pragma unroll
            for (int i = 0; i < 4; ++i)
                a2[i] = *(const bf16x8*)&Al[(wmm + i * 16 + lr) * TK + ks * 32 + lk * 8];
#pragma unroll
            for (int j = 0; j < 4; ++j)
                b2[j] = *(const bf16x8*)&Bl[(wnn + j * 16 + lr) * TK + ks * 32 + lk * 8];
#pragma unroll
            for (int i = 0; i < 4; ++i)
#pragma unroll
                for (int j = 0; j < 4; ++j)
                    acc[i][j] = __builtin_amdgcn_mfma_f32_16x16x32_bf16(
                        a2[i], b2[j], acc[i][j], 0, 0, 0);
        }
        __syncthreads();
        ga += TK; gb += TK;
    }
    const int rowb = lk * 4;
#pragma unroll
    for (int i = 0; i < 4; ++i)
#pragma unroll
        for (int j = 0; j < 4; ++j) {
            const int col = bn * TN + wnn + j * 16 + lr;
            float* yp = Y + (size_t)(bm * TM + wmm + i * 16 + rowb) * N + col;
#pragma unroll
            for (int r = 0; r < 4; ++r)
                yp[(size_t)r * N] = acc[i][j][r];
        }
}

// ---------------- fallback: round-1 fused kernel (tiny ws) ----------------
__global__ __launch_bounds__(256, 2)
void qlin_fused(const float* __restrict__ X, const int* __restrict__ Q,
                const float* __restrict__ S, const float* __restrict__ Z,
                float* __restrict__ Y, int M, int N, int K, int G)
{
    __shared__ __attribute__((aligned(16))) __bf16 Al[TM * TK];
    __shared__ __attribute__((aligned(16))) __bf16 Bl[TN * TK];

    const int tid = threadIdx.x;
    const int nbn = N / TN;
    const int bm = blockIdx.x / nbn;
    const int bn = blockIdx.x % nbn;

    const float* ap[4];
    const int*   qp[4];
    int nIdx[4], ldsOff[4];
#pragma unroll
    for (int i = 0; i < 4; ++i) {
        const int c   = tid + i * 256;
        const int row = c >> 3;
        const int c8  = c & 7;
        ldsOff[i] = row * TK + (c8 ^ (row & 7)) * 8;
        ap[i]   = X + (size_t)(bm * TM + row) * K + c8 * 8;
        qp[i]   = Q + (size_t)(bn * TN + row) * K + c8 * 8;
        nIdx[i] = bn * TN + row;
    }
    const int lane = tid & 63;
    const int wv   = tid >> 6;
    const int wmm  = (wv >> 1) * 64;
    const int wnn  = (wv & 1) * 64;
    const int lr   = lane & 15;
    const int lk   = lane >> 4;

    f32x4 acc[4][4] = {};
    const int ntile = K / TK;
    const int gstep = G / TK;
    int g = 0, gc = 0;
    for (int t = 0; t < ntile; ++t) {
#pragma unroll
        for (int i = 0; i < 4; ++i) {
            const float4 v0 = *(const float4*)(ap[i]);
            const float4 v1 = *(const float4*)(ap[i] + 4);
            bf16x8 u;
            u[0] = (__bf16)v0.x; u[1] = (__bf16)v0.y;
            u[2] = (__bf16)v0.z; u[3] = (__bf16)v0.w;
            u[4] = (__bf16)v1.x; u[5] = (__bf16)v1.y;
            u[6] = (__bf16)v1.z; u[7] = (__bf16)v1.w;
            *(bf16x8*)&Al[ldsOff[i]] = u;
            ap[i] += TK;
        }
#pragma unroll
        for (int i = 0; i < 4; ++i) {
            const int4 q0 = *(const int4*)(qp[i]);
            const int4 q1 = *(const int4*)(qp[i] + 4);
            const float s = S[(size_t)g * N + nIdx[i]];
            const float z = Z[(size_t)g * N + nIdx[i]];
            bf16x8 u;
            u[0] = (__bf16)((float)q0.x * s + z);
            u[1] = (__bf16)((float)q0.y * s + z);
            u[2] = (__bf16)((float)q0.z * s + z);
            u[3] = (__bf16)((float)q0.w * s + z);
            u[4] = (__bf16)((float)q1.x * s + z);
            u[5] = (__bf16)((float)q1.y * s + z);
            u[6] = (__bf16)((float)q1.z * s + z);
            u[7] = (__bf16)((float)q1.w * s + z);
            *(bf16x8*)&Bl[ldsOff[i]] = u;
            qp[i] += TK;
        }
        __syncthreads();
#pragma unroll
        for (int ks = 0; ks < 2; ++ks) {
            bf16x8 a2[4], b2[4];
#pragma unroll
            for (int i = 0; i < 4; ++i) {
                const int row = wmm + i * 16 + lr;
                a2[i] = *(const bf16x8*)&Al[row * TK + ((ks * 4 + lk) ^ (row & 7)) * 8];
            }
#pragma unroll
            for (int j = 0; j < 4; ++j) {
                const int row = wnn + j * 16 + lr;
                b2[j] = *(const bf16x8*)&Bl[row * TK + ((ks * 4 + lk) ^ (row & 7)) * 8];
            }
#pragma unroll
            for (int i = 0; i < 4; ++i)
#pragma unroll
                for (int j = 0; j < 4; ++j)
                    acc[i][j] = __builtin_amdgcn_mfma_f32_16x16x32_bf16(
                        a2[i], b2[j], acc[i][j], 0, 0, 0);
        }
        __syncthreads();
        if (++gc == gstep) { gc = 0; ++g; }
    }
    const int rowb = lk * 4;
#pragma unroll
    for (int i = 0; i < 4; ++i)
#pragma unroll
        for (int j = 0; j < 4; ++j) {
            const int col = bn * TN + wnn + j * 16 + lr;
            float* yp = Y + (size_t)(bm * TM + wmm + i * 16 + rowb) * N + col;
#pragma unroll
            for (int r = 0; r < 4; ++r)
                yp[(size_t)r * N] = acc[i][j][r];
        }
}

extern "C" void kernel_launch(void* const* d_in, const int* in_sizes, int n_in,
                              void* d_out, int out_size, void* d_ws, size_t ws_size,
                              hipStream_t stream)
{
    const float* X  = (const float*)d_in[0];
    const int*   Q  = (const int*)d_in[1];
    const float* S  = (const float*)d_in[2];
    const float* Z  = (const float*)d_in[3];
    float*       Y  = (float*)d_out;

    const long long MK = in_sizes[0];
    const long long NK = in_sizes[1];
    const long long GN = in_sizes[2];
    const int G = (int)(NK / GN);
    const long long kk = NK * MK / (long long)out_size;
    const int K = (int)llround(sqrt((double)kk));
    const int M = (int)(MK / K);
    const int N = (int)(NK / K);

    const size_t need = ((size_t)M * K + (size_t)N * K) * sizeof(__bf16);
    if (ws_size >= need) {
        __bf16* Xbf = (__bf16*)d_ws;
        __bf16* Wbf = Xbf + (size_t)M * K;
        prep_ab<<<2048, 256, 0, stream>>>(X, Q, S, Z, Xbf, Wbf,
                                          (long)M * K / 8, N, K, G);

        bool done = false;
        if ((M % 256 == 0) && (N % 256 == 0) && (K % 128 == 0) && (K >= 256)) {
            (void)hipFuncSetAttribute((const void*)gemm8ph,
                                      hipFuncAttributeMaxDynamicSharedMemorySize,
                                      131072);
            (void)hipGetLastError();   // clear
            gemm8ph<<<(M / 256) * (N / 256), 512, 131072, stream>>>(Xbf, Wbf, Y, M, N, K);
            done = (hipGetLastError() == hipSuccess);
        }
        if (!done) {
            gemm_bf16_bt<<<(M / TM) * (N / TN), 256, 0, stream>>>(Xbf, Wbf, Y, M, N, K);
        }
    } else {
        qlin_fused<<<(M / TM) * (N / TN), 256, 0, stream>>>(X, Q, S, Z, Y, M, N, K, G);
    }
}